// Round 6
// baseline (3613.266 us; speedup 1.0000x reference)
//
#include <hip/hip_runtime.h>
#include <cmath>

// Problem constants (fixed by setup_inputs)
constexpr int B = 32, S = 1024, I = 512, H = 1024;
constexpr float DT = 0.05f;
// Canary: +/-2.0f (sign bit may carry a data dependency; consumers check the
// magnitude). Exchanged values are h with |h| <= ~1.0000001, so any bit
// pattern with magnitude 2.0 (0x40000000) is unreachable by real data.
constexpr unsigned CANARY = 0x40000000u;

// packed-math friendly 2-wide float vector (per-component fma == fmaf:
// bit-exact vs scalar; backend may fuse to v_pk_fma_f32)
typedef float v2f __attribute__((ext_vector_type(2)));

__device__ __forceinline__ v2f fmav(v2f a, v2f b, v2f c) {
#if __has_builtin(__builtin_elementwise_fma)
    return __builtin_elementwise_fma(a, b, c);
#else
    v2f r;
    r.x = fmaf(a.x, b.x, c.x);
    r.y = fmaf(a.y, b.y, c.y);
    return r;
#endif
}

// ---------------------------------------------------------------------------
// Phase 1: h_in_all[M=B*S][H] = x[M][I] @ W_in[I][H], fp32, written into the
// `outs` region of d_out (the scan consumes/overwrites it in place). Unchanged.
// ---------------------------------------------------------------------------
__global__ __launch_bounds__(256) void gemm_in(const float* __restrict__ A,
                                               const float* __restrict__ Bw,
                                               float* __restrict__ C) {
    const int bx = blockIdx.x;
    const int nb = bx & 15;
    const int mb = bx >> 4;
    const int t  = threadIdx.x;
    const int tx = t & 15, ty = t >> 4;

    __shared__ __align__(16) float As[16][68];
    __shared__ __align__(16) float Bs[16][68];

    float acc[4][4] = {};
    const int row0 = mb * 64, col0 = nb * 64;

    for (int kt = 0; kt < I; kt += 16) {
        {
            const int m  = t >> 2;
            const int kq = (t & 3) * 4;
            const float4 a = *(const float4*)(A + (size_t)(row0 + m) * I + kt + kq);
            As[kq + 0][m] = a.x; As[kq + 1][m] = a.y;
            As[kq + 2][m] = a.z; As[kq + 3][m] = a.w;
            const int kk = t >> 4;
            const int n4 = (t & 15) * 4;
            *(float4*)&Bs[kk][n4] =
                *(const float4*)(Bw + (size_t)(kt + kk) * H + col0 + n4);
        }
        __syncthreads();
#pragma unroll
        for (int kk = 0; kk < 16; ++kk) {
            const float4 av = *(const float4*)&As[kk][ty * 4];
            const float4 bv = *(const float4*)&Bs[kk][tx * 4];
            const float ar[4] = {av.x, av.y, av.z, av.w};
            const float br[4] = {bv.x, bv.y, bv.z, bv.w};
#pragma unroll
            for (int i = 0; i < 4; ++i)
#pragma unroll
                for (int j = 0; j < 4; ++j) acc[i][j] += ar[i] * br[j];
        }
        __syncthreads();
    }
#pragma unroll
    for (int i = 0; i < 4; ++i) {
        float4 v = make_float4(acc[i][0], acc[i][1], acc[i][2], acc[i][3]);
        *(float4*)(C + (size_t)(row0 + ty * 4 + i) * H + col0 + tx * 4) = v;
    }
}

// agent-scope relaxed primitives (device-coherent; proven rounds 2/4/5)
__device__ __forceinline__ void sta(float* p, float v) {
    __hip_atomic_store(p, v, __ATOMIC_RELAXED, __HIP_MEMORY_SCOPE_AGENT);
}
__device__ __forceinline__ unsigned long long ld2(const float* p) {
    return __hip_atomic_load((const unsigned long long*)p, __ATOMIC_RELAXED,
                             __HIP_MEMORY_SCOPE_AGENT);
}
__device__ __forceinline__ void stc(float* p, unsigned v) {
    __hip_atomic_store((unsigned*)p, v, __ATOMIC_RELAXED,
                       __HIP_MEMORY_SCOPE_AGENT);
}
__device__ __forceinline__ float uf(unsigned x) { return __uint_as_float(x); }
// magnitude-masked canary check (canary sign bit may carry data dependency)
__device__ __forceinline__ bool has_canary(unsigned long long q) {
    return (((unsigned)q & 0x7FFFFFFFu) == CANARY) ||
           (((unsigned)(q >> 32) & 0x7FFFFFFFu) == CANARY);
}

// ---------------------------------------------------------------------------
// Phase 2 scan — canary dataflow (round-4/5 proven), single barrier per step,
// plus two symmetric-pipeline refinements (both FP-bit-exact vs round 5):
//   * reduce/publish distributed across ALL 8 waves: active thread t&3==0
//     owns output o=t>>2 and performs the EXACT serial q=0..31 partial sum
//     (identical association => identical bits). All waves publish and then
//     re-enter their poll together: removes the waves-0/1 straggler that
//     made barrier B wait an extra reduce+poll round trip.
//   * partials accumulate in v2f with per-component fma (v_pk_fma_f32
//     candidate): halves VALU instruction count in the inner loop.
// Protocol recap: data IS the flag. Producer: canary(s+1, own slot) issued
// before barrier B (whose mandatory vmcnt(0) drains it to L3), h(s) stored
// after barrier B => consumers polling slot(s) for non-canary magnitude can
// never observe pre-canary garbage at slot(s+1). part[] double-buffered by
// parity; single barrier B per step makes the buffer swap safe (all waves
// finished reading part[s&1] before any wave can pass B(s) and overwrite
// part[(s+1)&1]=part[(s-1)&1]).
// h_lds hazard: stagers of chunk ks==slot overwrite the own-slot region only
// after observing this block's OWN h(s) publish, which each publisher issues
// strictly after its hp read (program order + data dependency).
// ---------------------------------------------------------------------------
__global__ __launch_bounds__(512, 1) void scan_k(const float* __restrict__ Wrec,
                                                 const float* __restrict__ bias,
                                                 const float* __restrict__ tau,
                                                 float* __restrict__ out,
                                                 int* __restrict__ ws) {
    const int t    = threadIdx.x;
    const int bid  = blockIdx.x;
    const int rep  = bid & 7;
    const int slot = bid >> 3;
    const int b0   = rep * 4;
    const int c0   = slot * 32;

    const int ks  = t >> 4;       // 0..31: k-chunk = producer slot index
    const int cq2 = t & 15;       // 0..15: 2-col group

    __shared__ __align__(16) float h_lds[4 * 1152];     // [b][k] padded, 18.4KB
    __shared__ __align__(16) float part[2][32 * 132];   // dbuf, 33.8KB

    int* const flags   = ws;                                    // 32 KB
    int* const myflag  = flags + (((rep << 5) | ks) << 5);      // my producer
    int* const pubflag = flags + (((rep << 5) | slot) << 5);    // my own

    // ---- one-time: W slice into registers (32 k x 2 cols = 64 VGPR) ----
    const int cc = c0 + cq2 * 2;
    v2f wreg[32];
#pragma unroll
    for (int kk = 0; kk < 32; ++kk)
        wreg[kk] = *(const v2f*)&Wrec[(size_t)(ks * 32 + kk) * H + cc];

    // ---- per-output constants for the distributed reduce (t&3==0) ----
    const bool act = ((t & 3) == 0);
    const int o  = t >> 2;                 // 0..127: output index
    const int br = o >> 5, jc = o & 31;    // batch-in-group, col-in-group
    const int c  = c0 + jc;
    float al = 0.f, bi = 0.f;
    if (act) { al = __expf(-DT / tau[c]); bi = bias[c]; }
    const size_t obase = (size_t)(b0 + br) * S * H + c;

    const int wa2 = 2 * t + ks * 4;   // LDS dword offset of k=2t (padded)

    // ---- prologue: capture hin(0), canary slot(0), publish readiness ----
    float hinCur = 0.f;
    if (act) hinCur = out[obase];            // hin(0), plain load
    __syncthreads();                         // vmcnt(0): load complete
    if (act) stc(&out[obase], CANARY);       // canary slot(0)
    __syncthreads();                         // vmcnt(0): canary at L3
    if (t == 0)
        __hip_atomic_store(pubflag, 1, __ATOMIC_RELAXED,
                           __HIP_MEMORY_SCOPE_AGENT);

    for (int s = 0; s < S; ++s) {
        // next-step hin load early (own data; never crosses blocks)
        float hinNext = 0.f;
        if (act && s + 1 < S) hinNext = out[obase + (size_t)(s + 1) * H];

        if (s == 0) {
            const v2f z = {0.f, 0.f};
#pragma unroll
            for (int bb = 0; bb < 4; ++bb)
                *(v2f*)&h_lds[bb * 1152 + wa2] = z;
        } else {
            if (s == 1) {  // one-time: producer's prologue canary is at L3
                while (__hip_atomic_load(myflag, __ATOMIC_RELAXED,
                                         __HIP_MEMORY_SCOPE_AGENT) < 1)
                    __builtin_amdgcn_s_sleep(1);
            }
            // ---- data-poll: 8 h values (4 batches x k=2t..2t+1) ----
            const float* src = out + (size_t)(s - 1) * H + 2 * t;
            const float* p0 = src + (size_t)(b0 + 0) * S * H;
            const float* p1 = src + (size_t)(b0 + 1) * S * H;
            const float* p2 = src + (size_t)(b0 + 2) * S * H;
            const float* p3 = src + (size_t)(b0 + 3) * S * H;
            unsigned long long q0, q1, q2, q3;
            for (;;) {
                q0 = ld2(p0); q1 = ld2(p1); q2 = ld2(p2); q3 = ld2(p3);
                const bool bad = has_canary(q0) | has_canary(q1) |
                                 has_canary(q2) | has_canary(q3);
                if (!bad) break;
                __builtin_amdgcn_s_sleep(1);
            }
            *(v2f*)&h_lds[0 * 1152 + wa2] =
                (v2f){uf((unsigned)q0), uf((unsigned)(q0 >> 32))};
            *(v2f*)&h_lds[1 * 1152 + wa2] =
                (v2f){uf((unsigned)q1), uf((unsigned)(q1 >> 32))};
            *(v2f*)&h_lds[2 * 1152 + wa2] =
                (v2f){uf((unsigned)q2), uf((unsigned)(q2 >> 32))};
            *(v2f*)&h_lds[3 * 1152 + wa2] =
                (v2f){uf((unsigned)q3), uf((unsigned)(q3 >> 32))};
        }

        // canary next step's own slot; value depends on hinNext (sign bit)
        // so the store cannot pass the outstanding hinNext load.
        if (act && s + 1 < S) {
            const unsigned cb =
                CANARY | (__float_as_uint(hinNext) & 0x80000000u);
            stc(&out[obase + (size_t)(s + 1) * H], cb);
        }

        // ---- partials: 4 b x 2 c over my 32 k (wave-local LDS data) ----
        v2f a0 = {0.f, 0.f};
        v2f a1 = a0, a2 = a0, a3 = a0;
#pragma unroll
        for (int kq = 0; kq < 8; ++kq) {
            const int ha = ks * 36 + kq * 4;
            const float4 h0 = *(const float4*)&h_lds[ha];
            const float4 h1 = *(const float4*)&h_lds[1152 + ha];
            const float4 h2 = *(const float4*)&h_lds[2304 + ha];
            const float4 h3 = *(const float4*)&h_lds[3456 + ha];
            const float r0[4] = {h0.x, h0.y, h0.z, h0.w};
            const float r1[4] = {h1.x, h1.y, h1.z, h1.w};
            const float r2[4] = {h2.x, h2.y, h2.z, h2.w};
            const float r3[4] = {h3.x, h3.y, h3.z, h3.w};
#pragma unroll
            for (int j = 0; j < 4; ++j) {
                const v2f w = wreg[kq * 4 + j];
                a0 = fmav((v2f){r0[j], r0[j]}, w, a0);
                a1 = fmav((v2f){r1[j], r1[j]}, w, a1);
                a2 = fmav((v2f){r2[j], r2[j]}, w, a2);
                a3 = fmav((v2f){r3[j], r3[j]}, w, a3);
            }
        }
        {
            float* pp = &part[s & 1][ks * 132 + cq2 * 2];
            *(v2f*)(pp +  0) = a0;
            *(v2f*)(pp + 32) = a1;
            *(v2f*)(pp + 64) = a2;
            *(v2f*)(pp + 96) = a3;
        }
        __syncthreads();   // B — partials visible; canary at L3 (vmcnt(0))

        // ---- distributed reduce (exact serial order), tanh, blend, publish
        if (act) {
            const float* pb = &part[s & 1][0];
            float sum = 0.f;
#pragma unroll
            for (int q = 0; q < 32; ++q) sum += pb[q * 132 + o];
            const float z  = hinCur + sum + bi;
            const float e2 = __expf(2.f * z);
            const float ht = 1.f - 2.f / (e2 + 1.f);   // tanh(z)
            const float hp = h_lds[br * 1152 + slot * 36 + jc];
            const float hn = al * hp + (1.f - al) * ht;
            sta(&out[obase + (size_t)s * H], hn);
            if (s == S - 1)
                out[(size_t)B * S * H + (size_t)(b0 + br) * H + c] = hn;
        }
        hinCur = hinNext;
        // no tail barrier, no staging barrier: waves gate themselves on the
        // canary data; part is double-buffered; h_lds regions are wave-local.
    }
}

// ---------------------------------------------------------------------------
extern "C" void kernel_launch(void* const* d_in, const int* in_sizes, int n_in,
                              void* d_out, int out_size, void* d_ws, size_t ws_size,
                              hipStream_t stream) {
    (void)in_sizes; (void)n_in; (void)out_size;
    const float* x    = (const float*)d_in[0];
    const float* W_in = (const float*)d_in[1];
    const float* Wrec = (const float*)d_in[2];
    const float* bs   = (const float*)d_in[3];
    const float* tu   = (const float*)d_in[4];
    float* outp = (float*)d_out;
    int*   bwsp = (int*)d_ws;

    // zero flag region (defensive; logic is poison-tolerant either way)
    size_t zb = 256 * 32 * sizeof(int);
    if (zb > ws_size) zb = ws_size;
    (void)hipMemsetAsync(d_ws, 0, zb, stream);

    gemm_in<<<dim3(512 * 16), dim3(256), 0, stream>>>(x, W_in, outp);

    void* kargs[5] = {(void*)&Wrec, (void*)&bs, (void*)&tu, (void*)&outp,
                      (void*)&bwsp};
    (void)hipLaunchCooperativeKernel((void*)scan_k, dim3(256), dim3(512), kargs,
                                     0, stream);
}